// Round 18
// baseline (493.452 us; speedup 1.0000x reference)
//
#include <hip/hip_runtime.h>

typedef unsigned short ushort_t;
typedef __attribute__((ext_vector_type(8))) short bs8;       // 8 x bf16 (4 VGPR)
typedef __attribute__((ext_vector_type(4))) float f32x4;
typedef __attribute__((ext_vector_type(4))) unsigned short u16x4;

#define DEV __device__ __forceinline__

DEV unsigned short f2bf(float f){
  unsigned u = __float_as_uint(f);
  u += 0x7fffu + ((u >> 16) & 1u);           // round-to-nearest-even
  return (unsigned short)(u >> 16);
}
DEV float bf2f(unsigned short h){ return __uint_as_float(((unsigned)h) << 16); }

DEV unsigned cvt_pk_bf16(float lo, float hi){
  unsigned r;
  asm volatile("v_cvt_pk_bf16_f32 %0, %1, %2" : "=v"(r) : "v"(lo), "v"(hi));
  return r;
}

DEV void gl2lds16(const void* g, void* l){
  __builtin_amdgcn_global_load_lds((const __attribute__((address_space(1))) void*)g,
                                   (__attribute__((address_space(3))) void*)l, 16, 0, 0);
}

DEV void st_out(ushort_t* C, size_t i, float v){ C[i] = f2bf(v); }
DEV void st_out(float*    C, size_t i, float v){ C[i] = v; }

// ---- prep1: x cast (bid < 8192) + GEMM1's weight transposes (dq/dkv/kr) ----
__global__ __launch_bounds__(256) void prep1(
    const float* __restrict__ x, ushort_t* __restrict__ xb,
    const float* __restrict__ s0, const float* __restrict__ s1,
    const float* __restrict__ s2,
    ushort_t* __restrict__ d0, ushort_t* __restrict__ d1,
    ushort_t* __restrict__ d2){
  const int bid = blockIdx.x;
  if (bid < 8192){
    size_t i = ((size_t)bid * 256 + threadIdx.x) * 4;
    float4 v = *(const float4*)(x + i);
    u16x4 o;
    o[0] = f2bf(v.x); o[1] = f2bf(v.y); o[2] = f2bf(v.z); o[3] = f2bf(v.w);
    *(u16x4*)(xb + i) = o;
    return;
  }
  __shared__ float tile[32][33];
  const float* src; ushort_t* dst; int K, N, loc;
  if      (bid < 10240){ src=s0; dst=d0; K=2048; N=1024; loc=bid-8192;  }   // w_dq
  else if (bid < 11264){ src=s1; dst=d1; K=2048; N=512;  loc=bid-10240; }   // w_dkv
  else                 { src=s2; dst=d2; K=2048; N=1024; loc=bid-11264; }   // w_kr
  const int nx = N >> 5;
  const int n0 = (loc % nx) << 5, k0 = (loc / nx) << 5;
  const int tx = threadIdx.x & 31, ty = threadIdx.x >> 5;
  for (int r = ty; r < 32; r += 8)
    tile[r][tx] = src[(size_t)(k0 + r) * N + n0 + tx];
  __syncthreads();
  for (int r = ty; r < 32; r += 8)
    dst[(size_t)(n0 + r) * K + k0 + tx] = f2bf(tile[tx][r]);
}

// ================= 256x256 8-phase GEMM core (T2+T3+T4+T5), BK=64 =================
DEV void gemm_core(const ushort_t* __restrict__ A, int lda,
                   const ushort_t* __restrict__ BT, int K,
                   int m0, int n0, ushort_t* lds, f32x4 (&acc)[8][4]){
  const int tid = threadIdx.x, lane = tid & 63, wid = tid >> 6;
  const int l15 = lane & 15, lhi = lane >> 4;
  const int wr = wid >> 2, wc = wid & 3;

  const int trow = tid >> 3;
  const int tcsrc = (tid & 7) ^ (trow & 7);
  const ushort_t* gA[2][2];
  const ushort_t* gB[2][2];
#pragma unroll
  for (int h = 0; h < 2; ++h)
#pragma unroll
    for (int i = 0; i < 2; ++i){
      gA[h][i] = A  + (size_t)(m0 + h * 128 + i * 64 + trow) * lda + tcsrc * 8;
      gB[h][i] = BT + (size_t)(n0 + h * 128 + i * 64 + trow) * K   + tcsrc * 8;
    }

  auto STAGE_A = [&](int buf, int h, int kt){
    gl2lds16(gA[h][0] + (size_t)kt * 64, lds + buf * 32768 + h * 8192 + tid * 8);
    gl2lds16(gA[h][1] + (size_t)kt * 64, lds + buf * 32768 + h * 8192 + 4096 + tid * 8);
  };
  auto STAGE_B = [&](int buf, int h, int kt){
    gl2lds16(gB[h][0] + (size_t)kt * 64, lds + buf * 32768 + 16384 + h * 8192 + tid * 8);
    gl2lds16(gB[h][1] + (size_t)kt * 64, lds + buf * 32768 + 16384 + h * 8192 + 4096 + tid * 8);
  };

  const int ck0 = ((lhi) ^ (l15 & 7)) << 3;
  const int ck1 = ((4 + lhi) ^ (l15 & 7)) << 3;

  bs8 aF[4][2], bLo[2][2], bHi[2][2];

  auto RDA = [&](int buf, int mq){
#pragma unroll
    for (int m = 0; m < 4; ++m){
      const ushort_t* r = lds + buf * 32768 + wr * 8192 + ((mq + m) * 16 + l15) * 64;
      aF[m][0] = *(const bs8*)(r + ck0);
      aF[m][1] = *(const bs8*)(r + ck1);
    }
  };
  auto RDB = [&](int buf, int nq, bs8 (&br)[2][2]){
#pragma unroll
    for (int n = 0; n < 2; ++n){
      const ushort_t* r = lds + buf * 32768 + 16384 + (wc >> 1) * 8192 +
                          ((wc & 1) * 64 + (nq + n) * 16 + l15) * 64;
      br[n][0] = *(const bs8*)(r + ck0);
      br[n][1] = *(const bs8*)(r + ck1);
    }
  };
  auto MMA = [&](int mq, int nq, bs8 (&br)[2][2]){
    __builtin_amdgcn_s_setprio(1);
#pragma unroll
    for (int m = 0; m < 4; ++m)
#pragma unroll
      for (int n = 0; n < 2; ++n){
        acc[mq + m][nq + n] = __builtin_amdgcn_mfma_f32_16x16x32_bf16(aF[m][0], br[n][0], acc[mq + m][nq + n], 0, 0, 0);
        acc[mq + m][nq + n] = __builtin_amdgcn_mfma_f32_16x16x32_bf16(aF[m][1], br[n][1], acc[mq + m][nq + n], 0, 0, 0);
      }
    __builtin_amdgcn_s_setprio(0);
  };

#define BAR() __builtin_amdgcn_s_barrier()
#define LGK() asm volatile("s_waitcnt lgkmcnt(0)" ::: "memory")
#define VMC4() asm volatile("s_waitcnt vmcnt(4)" ::: "memory")

  const int nkt = K >> 6;
  const int nIter = K >> 7;

  STAGE_A(0, 0, 0); STAGE_A(0, 1, 0); STAGE_B(0, 0, 0); STAGE_B(0, 1, 0);
  STAGE_B(1, 0, 1); STAGE_B(1, 1, 1);
  VMC4();
  BAR();

  for (int it = 0; it < nIter; ++it){
    const int kt1 = 2 * it + 1;
    int kt2 = 2 * it + 2; if (kt2 > nkt - 1) kt2 = nkt - 1;
    int kt3 = 2 * it + 3; if (kt3 > nkt - 1) kt3 = nkt - 1;
    RDA(0, 0); RDB(0, 0, bLo);
    STAGE_A(1, 0, kt1);
    BAR(); LGK(); MMA(0, 0, bLo); BAR();
    RDB(0, 2, bHi);
    STAGE_A(1, 1, kt1);
    BAR(); LGK(); MMA(0, 2, bHi); BAR();
    RDA(0, 4);
    STAGE_B(0, 0, kt2);
    BAR(); LGK(); MMA(4, 0, bLo); BAR();
    STAGE_B(0, 1, kt2);
    BAR(); LGK(); MMA(4, 2, bHi);
    VMC4(); BAR();
    RDA(1, 0); RDB(1, 0, bLo);
    STAGE_A(0, 0, kt2);
    BAR(); LGK(); MMA(0, 0, bLo); BAR();
    RDB(1, 2, bHi);
    STAGE_A(0, 1, kt2);
    BAR(); LGK(); MMA(0, 2, bHi); BAR();
    RDA(1, 4);
    STAGE_B(1, 0, kt3);
    BAR(); LGK(); MMA(4, 0, bLo); BAR();
    STAGE_B(1, 1, kt3);
    BAR(); LGK(); MMA(4, 2, bHi);
    VMC4(); BAR();
  }
#undef BAR
#undef LGK
#undef VMC4
}

// EPI 1: comb1[4096][1536] + rope(kr)->Ka. EPI 2: Qa (qc+rope(qr)) pre-scaled.
// EPI 3: Ka(kc) + v transposed -> vT[bh][d][t].
template<int EPI, typename OT>
DEV void gemm_epi(f32x4 (&acc)[8][4], OT* __restrict__ C, int N, int m0, int n0,
                  ushort_t* __restrict__ aux,
                  const float* __restrict__ fcp, const float* __restrict__ fsp){
  const int tid = threadIdx.x, lane = tid & 63, wid = tid >> 6;
  const int l15 = lane & 15, lhi = lane >> 4;
  const int wr = wid >> 2, wc = wid & 3;
  const float SC = (EPI == 2) ? (0.07216878364870323f * 1.4426950408889634f) : 1.0f;
  const int RBASE = (EPI == 1) ? 1536 : 2048;
#pragma unroll
  for (int m = 0; m < 8; ++m){
    const int r = m0 + wr * 128 + m * 16 + lhi * 4;
#pragma unroll
    for (int n = 0; n < 4; ++n){
      const int c = n0 + wc * 64 + n * 16 + l15;
      if (EPI == 0){
#pragma unroll
        for (int j = 0; j < 4; ++j)
          st_out(C, (size_t)(r + j) * N + c, acc[m][n][j]);
      } else if ((EPI == 1 && c < 1536)){
#pragma unroll
        for (int j = 0; j < 4; ++j)
          C[(size_t)(r + j) * 1536 + c] = (OT)f2bf(acc[m][n][j]);
      } else if (EPI == 2 && c < 2048){
        int hh = c >> 7, d = c & 127;
#pragma unroll
        for (int j = 0; j < 4; ++j){
          int rr = r + j, bb = rr >> 11, tt = rr & 2047;
          aux[((size_t)(bb * 16 + hh) * 2048 + tt) * 192 + d] = f2bf(acc[m][n][j] * SC);
        }
      } else if (EPI == 3 && c < 2048){
        int hh = c >> 7, d = c & 127;
#pragma unroll
        for (int j = 0; j < 4; ++j){
          int rr = r + j, bb = rr >> 11, tt = rr & 2047;
          aux[((size_t)(bb * 16 + hh) * 2048 + tt) * 192 + d] = f2bf(acc[m][n][j]);
        }
      } else if (EPI == 3){
        int cv = c - 2048;
        int hh = cv >> 7, d = cv & 127;
        int bb = r >> 11, tt = r & 2047;
        u16x4 o;
#pragma unroll
        for (int j = 0; j < 4; ++j) o[j] = f2bf(acc[m][n][j]);
        *(u16x4*)((ushort_t*)C + ((size_t)(bb * 16 + hh) * 128 + d) * 2048 + tt) = o;
      } else {
        int cr = c - RBASE;
        int hh = cr >> 6, dr = cr & 63, ii = dr >> 1;
#pragma unroll
        for (int j = 0; j < 4; ++j){
          int rr = r + j, bb = rr >> 11, tt = rr & 2047;
          float v = acc[m][n][j] * SC;
          float pv = __shfl_xor(v, 1);
          float co = fcp[tt * 32 + ii], si = fsp[tt * 32 + ii];
          float o = (l15 & 1) ? fmaf(pv, si, v * co) : fmaf(-pv, si, v * co);
          aux[((size_t)(bb * 16 + hh) * 2048 + tt) * 192 + 128 + dr] = f2bf(o);
        }
      }
    }
  }
}

// GEMM1 (160 tiles) + 5 remaining weight transposes (9216 32x32 tiles, 2/block)
// fused into one 4768-block dispatch: the 96 CUs idle during GEMM1 absorb them.
__global__ __launch_bounds__(512, 2) void gemm1f(const ushort_t* __restrict__ A, int lda,
                                                 const ushort_t* __restrict__ BT,
                                                 ushort_t* __restrict__ C, int K,
                                                 ushort_t* __restrict__ aux,
                                                 const float* __restrict__ fcp,
                                                 const float* __restrict__ fsp,
                                                 const float* __restrict__ t0s, ushort_t* __restrict__ t0d,
                                                 const float* __restrict__ t1s, ushort_t* __restrict__ t1d,
                                                 const float* __restrict__ t2s, ushort_t* __restrict__ t2d,
                                                 const float* __restrict__ t3s, ushort_t* __restrict__ t3d,
                                                 const float* __restrict__ t4s, ushort_t* __restrict__ t4d){
  __shared__ __align__(16) ushort_t lds[65536];
  const int nwg = gridDim.x;                 // 4768 (% 8 == 0)
  const int orig = blockIdx.x;
  const int wg = (orig & 7) * (nwg >> 3) + (orig >> 3);
  if (wg < 160){
    const int m0 = (wg % 16) << 8;
    const int n0 = (wg / 16) << 8;
    f32x4 acc[8][4] = {};
    gemm_core(A, lda, BT, K, m0, n0, lds, acc);
    gemm_epi<1, ushort_t>(acc, C, 2560, m0, n0, aux, fcp, fsp);
    return;
  }
  // tcast route: two 32x32 tiles per block (one per 256-thread half)
  const int tid = threadIdx.x;
  const int tg = tid >> 8, tid2 = tid & 255;
  const int tileid = 2 * (wg - 160) + tg;    // [0, 9216)
  const float* src; ushort_t* dst; int K2, N2, loc;
  if      (tileid < 2048){ src=t0s; dst=t0d; K2=1024; N2=2048; loc=tileid; }         // w_uq
  else if (tileid < 3072){ src=t1s; dst=t1d; K2=1024; N2=1024; loc=tileid-2048; }    // w_qr
  else if (tileid < 4096){ src=t2s; dst=t2d; K2=512;  N2=2048; loc=tileid-3072; }    // w_uk
  else if (tileid < 5120){ src=t3s; dst=t3d; K2=512;  N2=2048; loc=tileid-4096; }    // w_uv
  else                   { src=t4s; dst=t4d; K2=2048; N2=2048; loc=tileid-5120; }    // w_o
  const int nx = N2 >> 5;
  const int n0 = (loc % nx) << 5, k0 = (loc / nx) << 5;
  float* tl = (float*)lds + tg * 1068;       // 32*33=1056 floats + pad
  const int tx = tid2 & 31, ty = tid2 >> 5;
  for (int r = ty; r < 32; r += 8)
    tl[r * 33 + tx] = src[(size_t)(k0 + r) * N2 + n0 + tx];
  __syncthreads();
  for (int r = ty; r < 32; r += 8)
    dst[(size_t)(n0 + r) * K2 + k0 + tx] = f2bf(tl[tx * 33 + r]);
}

// GEMM2 (192 blocks) + GEMM3 (256 blocks) fused: 448 blocks.
__global__ __launch_bounds__(512, 2) void gemm23(const ushort_t* __restrict__ A2,
                                                 const ushort_t* __restrict__ BT2,
                                                 const ushort_t* __restrict__ A3,
                                                 const ushort_t* __restrict__ BT3,
                                                 ushort_t* __restrict__ vT,
                                                 ushort_t* __restrict__ Qa,
                                                 ushort_t* __restrict__ Ka,
                                                 const float* __restrict__ fcp,
                                                 const float* __restrict__ fsp){
  __shared__ __align__(16) ushort_t lds[65536];
  const int nwg = gridDim.x;   // 448
  const int orig = blockIdx.x;
  const int wg = (orig & 7) * (nwg >> 3) + (orig >> 3);
  f32x4 acc[8][4] = {};
  if (wg < 192){
    const int m0 = (wg % 16) << 8, n0 = (wg / 16) << 8;
    gemm_core(A2, 1536, BT2, 1024, m0, n0, lds, acc);
    gemm_epi<2, ushort_t>(acc, nullptr, 3072, m0, n0, Qa, fcp, fsp);
  } else {
    const int g = wg - 192;
    const int m0 = (g % 16) << 8, n0 = (g / 16) << 8;
    gemm_core(A3, 1536, BT3, 512, m0, n0, lds, acc);
    gemm_epi<3, ushort_t>(acc, vT, 4096, m0, n0, Ka, fcp, fsp);
  }
}

// ============ GEMM4: 256x128-tile 8-phase core (BK=64), fp32 out, 256 blocks ============
__global__ __launch_bounds__(512, 1) void gemm4_128(const ushort_t* __restrict__ A, int lda,
                                                    const ushort_t* __restrict__ BT,
                                                    float* __restrict__ C,
                                                    int M, int N, int K){
  __shared__ __align__(16) ushort_t lds[49152];
  const int tid = threadIdx.x, lane = tid & 63, wid = tid >> 6;
  const int l15 = lane & 15, lhi = lane >> 4;
  const int wr = wid >> 1, wc = wid & 1;

  const int nbx = M >> 8;
  const int nwg = gridDim.x;
  const int orig = blockIdx.x;
  const int wg = (orig & 7) * (nwg >> 3) + (orig >> 3);
  const int m0 = (wg % nbx) << 8;
  const int n0 = (wg / nbx) << 7;

  const int trow = tid >> 3;
  const int tcsrc = (tid & 7) ^ (trow & 7);
  const ushort_t* gA[2][2];
  const ushort_t* gB[2];
#pragma unroll
  for (int h = 0; h < 2; ++h)
#pragma unroll
    for (int i = 0; i < 2; ++i)
      gA[h][i] = A + (size_t)(m0 + h * 128 + i * 64 + trow) * lda + tcsrc * 8;
#pragma unroll
  for (int i = 0; i < 2; ++i)
    gB[i] = BT + (size_t)(n0 + i * 64 + trow) * K + tcsrc * 8;

  auto STAGE_A = [&](int buf, int h, int kt){
    gl2lds16(gA[h][0] + (size_t)kt * 64, lds + buf * 24576 + h * 8192 + tid * 8);
    gl2lds16(gA[h][1] + (size_t)kt * 64, lds + buf * 24576 + h * 8192 + 4096 + tid * 8);
  };
  auto STAGE_B = [&](int buf, int kt){
    gl2lds16(gB[0] + (size_t)kt * 64, lds + buf * 24576 + 16384 + tid * 8);
    gl2lds16(gB[1] + (size_t)kt * 64, lds + buf * 24576 + 16384 + 4096 + tid * 8);
  };

  const int ck0 = ((lhi) ^ (l15 & 7)) << 3;
  const int ck1 = ((4 + lhi) ^ (l15 & 7)) << 3;

  f32x4 acc[4][4] = {};
  bs8 aF[2][2], bLo[2][2], bHi[2][2];

  auto RDA = [&](int buf, int mq){
#pragma unroll
    for (int m = 0; m < 2; ++m){
      const int rowin = (wr & 1) * 64 + (mq + m) * 16 + l15;
      const ushort_t* r = lds + buf * 24576 + (wr >> 1) * 8192 + rowin * 64;
      aF[m][0] = *(const bs8*)(r + ck0);
      aF[m][1] = *(const bs8*)(r + ck1);
    }
  };
  auto RDB = [&](int buf, int nq, bs8 (&br)[2][2]){
#pragma unroll
    for (int n = 0; n < 2; ++n){
      const int row = wc * 64 + (nq + n) * 16 + l15;
      const ushort_t* r = lds + buf * 24576 + 16384 + row * 64;
      br[n][0] = *(const bs8*)(r + ck0);
      br[n][1] = *(const bs8*)(r + ck1);
    }
  };
  auto MMA = [&](int mq, int nq, bs8 (&br)[2][2]){
    __builtin_amdgcn_s_setprio(1);
#pragma unroll
    for (int m = 0; m < 2; ++m)
#pragma unroll
      for (int n = 0; n < 2; ++n){
        acc[mq + m][nq + n] = __builtin_amdgcn_mfma_f32_16x16x32_bf16(aF[m][0], br[n][0], acc[mq + m][nq + n], 0, 0, 0);
        acc[mq + m][nq + n] = __builtin_amdgcn_mfma_f32_16x16x32_bf16(aF[m][1], br[n][1], acc[mq + m][nq + n], 0, 0, 0);
      }
    __builtin_amdgcn_s_setprio(0);
  };

#define BAR() __builtin_amdgcn_s_barrier()
#define LGK() asm volatile("s_waitcnt lgkmcnt(0)" ::: "memory")
#define VMC2() asm volatile("s_waitcnt vmcnt(2)" ::: "memory")

  const int nkt = K >> 6;
  const int nIter = K >> 7;

  STAGE_A(0, 0, 0); STAGE_A(0, 1, 0); STAGE_B(0, 0);
  STAGE_B(1, 1);
  VMC2();
  BAR();

  for (int it = 0; it < nIter; ++it){
    const int kt1 = 2 * it + 1;
    int kt2 = 2 * it + 2; if (kt2 > nkt - 1) kt2 = nkt - 1;
    int kt3 = 2 * it + 3; if (kt3 > nkt - 1) kt3 = nkt - 1;
    RDA(0, 0); RDB(0, 0, bLo);
    STAGE_A(1, 0, kt1);
    BAR(); LGK(); MMA(0, 0, bLo); BAR();
    RDB(0, 2, bHi);
    STAGE_A(1, 1, kt1);
    BAR(); LGK(); MMA(0, 2, bHi); BAR();
    RDA(0, 2);
    STAGE_B(0, kt2);
    BAR(); LGK(); MMA(2, 0, bLo); BAR();
    BAR(); LGK(); MMA(2, 2, bHi);
    VMC2(); BAR();
    RDA(1, 0); RDB(1, 0, bLo);
    STAGE_A(0, 0, kt2);
    BAR(); LGK(); MMA(0, 0, bLo); BAR();
    RDB(1, 2, bHi);
    STAGE_A(0, 1, kt2);
    BAR(); LGK(); MMA(0, 2, bHi); BAR();
    RDA(1, 2);
    STAGE_B(1, kt3);
    BAR(); LGK(); MMA(2, 0, bLo); BAR();
    BAR(); LGK(); MMA(2, 2, bHi);
    VMC2(); BAR();
  }
#undef BAR
#undef LGK
#undef VMC2

#pragma unroll
  for (int m = 0; m < 4; ++m){
    const int r = m0 + wr * 64 + m * 16 + lhi * 4;
#pragma unroll
    for (int n = 0; n < 4; ++n){
      const int c = n0 + wc * 64 + n * 16 + l15;
#pragma unroll
      for (int j = 0; j < 4; ++j)
        C[(size_t)(r + j) * N + c] = acc[m][n][j];
    }
  }
}

// ====== flash attention v10b: balanced pairing + max3 reduction tree ======
__global__ __launch_bounds__(512) void attn_kernel(const ushort_t* __restrict__ Qa,
                                                   const ushort_t* __restrict__ Ka,
                                                   const ushort_t* __restrict__ VT,
                                                   ushort_t* __restrict__ O){
  __shared__ __align__(16) ushort_t lds[40960];
  const int tid = threadIdx.x, lane = tid & 63, wid = tid >> 6;
  const int bh = blockIdx.x;
  const int y = blockIdx.y;
  const int qb = (y < 8) ? (15 - y) : (y - 8);   // CU pair sums to 15 everywhere
  const int b = bh >> 4, h = bh & 15;
  const int qm0 = qb << 7;
  const int nkt = 2 * qb + 2;
  const int l15 = lane & 15, lhi = lane >> 4;

  const ushort_t* Kbh = Ka + (size_t)bh * 2048 * 192;
  const ushort_t* Vbh = VT + (size_t)bh * 128 * 2048;

  const ushort_t* ksrc[3];
#pragma unroll
  for (int i = 0; i < 3; ++i){
    int c = i * 512 + tid;
    int row = c / 24, col = c % 24;
    int hk = (row & 3) | (((row >> 3) & 1) << 2);
    ksrc[i] = Kbh + (size_t)row * 192 + (col ^ hk) * 8;
  }
  const ushort_t* vsrc[2];
#pragma unroll
  for (int i = 0; i < 2; ++i){
    int c = i * 512 + tid;
    int d = c >> 3, col = c & 7;
    vsrc[i] = Vbh + (size_t)d * 2048 + (col ^ (d & 7)) * 8;
  }

  auto STAGE = [&](int kt, int buf){
#pragma unroll
    for (int i = 0; i < 3; ++i)
      gl2lds16(ksrc[i] + (size_t)kt * 12288, lds + buf * 12288 + (i * 512 + tid) * 8);
#pragma unroll
    for (int i = 0; i < 2; ++i)
      gl2lds16(vsrc[i] + kt * 64, lds + 24576 + buf * 8192 + (i * 512 + tid) * 8);
  };

  bs8 qf[6];
  {
    const size_t qrow = ((size_t)bh * 2048 + qm0 + wid * 16 + l15) * 192;
#pragma unroll
    for (int kc = 0; kc < 6; ++kc)
      qf[kc] = *(const bs8*)(Qa + qrow + kc * 32 + lhi * 8);
  }

  f32x4 acc[8] = {};
  float mrow = -1e30f, lrow = 0.f;

  const int mylast = 2 * qb + (wid >> 2);
  const int hkr = (l15 & 3) | (((l15 >> 2) & 1) << 2);

#define BARR() __builtin_amdgcn_s_barrier()
#define LGK0() asm volatile("s_waitcnt lgkmcnt(0)" ::: "memory")
#define VMC(n) asm volatile("s_waitcnt vmcnt(" #n ")" ::: "memory")

  STAGE(0, 0);
  STAGE(1, 1);
  VMC(5);
  BARR();

  for (int kt = 0; kt < nkt; ++kt){
    const int cur = kt & 1;
    const ushort_t* Kb = lds + cur * 12288;
    const ushort_t* Vb = lds + 24576 + cur * 8192;

    if (kt <= mylast){
      f32x4 s[4] = {};
      __builtin_amdgcn_s_setprio(1);
#pragma unroll
      for (int kc = 0; kc < 6; ++kc){
        bs8 kf4[4];
#pragma unroll
        for (int m = 0; m < 4; ++m){
          int row = ((m >> 1) << 5) + ((l15 >> 2) << 3) + ((m & 1) << 2) + (l15 & 3);
          kf4[m] = *(const bs8*)(Kb + row * 192 + (((kc * 4 + lhi) ^ hkr) << 3));
        }
#pragma unroll
        for (int m = 0; m < 4; ++m)
          s[m] = __builtin_amdgcn_mfma_f32_16x16x32_bf16(kf4[m], qf[kc], s[m], 0, 0, 0);
      }
      __builtin_amdgcn_s_setprio(0);

      const bool noMask = (kt * 64 + 63) <= (qm0 + wid * 16);
      const int qi = qm0 + wid * 16 + l15;
      if (!noMask){
#pragma unroll
        for (int m = 0; m < 4; ++m)
#pragma unroll
          for (int j = 0; j < 4; ++j){
            int ki = kt * 64 + ((m >> 1) << 5) + (lhi << 3) + ((m & 1) << 2) + j;
            if (ki > qi) s[m][j] = -3e38f;
          }
      }
      float r0 = fmaxf(fmaxf(s[0][0], s[0][1]), s[0][2]);
      float r1 = fmaxf(fmaxf(s[0][3], s[1][0]), s[1][1]);
      float r2 = fmaxf(fmaxf(s[1][2], s[1][3]), s[2][0]);
      float r3 = fmaxf(fmaxf(s[2][1], s[2][2]), s[2][3]);
      float r4 = fmaxf(fmaxf(s[3][0], s[3][1]), s[3][2]);
      float rmax = fmaxf(fmaxf(r0, r1), fmaxf(fmaxf(r2, r3), fmaxf(r4, s[3][3])));
      rmax = fmaxf(rmax, __shfl_xor(rmax, 16));
      rmax = fmaxf(rmax, __shfl_xor(rmax, 32));
      if (!__all(rmax <= mrow + 8.f)){
        float mnew = fmaxf(mrow, rmax);
        float osc = exp2f(mrow - mnew);
        lrow *= osc;
#pragma unroll
        for (int f = 0; f < 8; ++f) acc[f] *= osc;
        mrow = mnew;
      }
      float rsum = 0.f;
#pragma unroll
      for (int m = 0; m < 4; ++m)
#pragma unroll
        for (int j = 0; j < 4; ++j){
          float pv = exp2f(s[m][j] - mrow);
          s[m][j] = pv;
          rsum += pv;
        }
      rsum += __shfl_xor(rsum, 16);
      rsum += __shfl_xor(rsum, 32);
      lrow += rsum;

      bs8 pb[2];
#pragma unroll
      for (int kc2 = 0; kc2 < 2; ++kc2){
        union { bs8 v; unsigned u[4]; } pu;
#pragma unroll
        for (int half = 0; half < 2; ++half){
          const f32x4& sv = s[2 * kc2 + half];
          pu.u[2 * half]     = cvt_pk_bf16(sv[0], sv[1]);
          pu.u[2 * half + 1] = cvt_pk_bf16(sv[2], sv[3]);
        }
        pb[kc2] = pu.v;
      }

      __builtin_amdgcn_s_setprio(1);
#pragma unroll
      for (int kc2 = 0; kc2 < 2; ++kc2)
#pragma unroll
        for (int f = 0; f < 8; ++f){
          bs8 vf = *(const bs8*)(Vb + (f * 16 + l15) * 64 + (((kc2 * 4 + lhi) ^ (l15 & 7)) << 3));
          acc[f] = __builtin_amdgcn_mfma_f32_16x16x32_bf16(vf, pb[kc2], acc[f], 0, 0, 0);
        }
      __builtin_amdgcn_s_setprio(0);
    }

    LGK0();
    BARR();
    if (kt + 2 < nkt){
      STAGE(kt + 2, cur);
      VMC(5);
    } else {
      VMC(0);
    }
    BARR();
  }
#undef BARR
#undef LGK0
#undef VMC

  {
    float rl = 1.0f / lrow;
    int t = qm0 + wid * 16 + l15;
#pragma unroll
    for (int f = 0; f < 8; ++f){
      u16x4 o;
#pragma unroll
      for (int j = 0; j < 4; ++j) o[j] = f2bf(acc[f][j] * rl);
      *(u16x4*)(O + ((size_t)b * 2048 + t) * 2048 + h * 128 + f * 16 + lhi * 4) = o;
    }
  }
}

extern "C" void kernel_launch(void* const* d_in, const int* in_sizes, int n_in,
                              void* d_out, int out_size, void* d_ws, size_t ws_size,
                              hipStream_t stream){
  constexpr int Bc = 2, Tc = 2048, Cc = 2048, Hc = 16, HDc = 128, RDc = 64, KVRc = 512, QRc = 1024;
  constexpr int Mx = Bc * Tc; // 4096
  const float* x     = (const float*)d_in[0];
  const float* w_dq  = (const float*)d_in[1];
  const float* w_uq  = (const float*)d_in[2];
  const float* w_dkv = (const float*)d_in[3];
  const float* w_uk  = (const float*)d_in[4];
  const float* w_uv  = (const float*)d_in[5];
  const float* w_qr  = (const float*)d_in[6];
  const float* w_kr  = (const float*)d_in[7];
  const float* w_o   = (const float*)d_in[8];
  const float* fc    = (const float*)d_in[9];
  const float* fs    = (const float*)d_in[10];
  float* out = (float*)d_out;

  char* ws = (char*)d_ws;
  size_t off = 0;
  auto alloc = [&](size_t elems) -> ushort_t* {
    ushort_t* p = (ushort_t*)(ws + off);
    off += ((elems * 2) + 255) & ~(size_t)255;
    return p;
  };
  ushort_t* xb    = alloc((size_t)Mx * Cc);
  ushort_t* wdqT  = alloc((size_t)QRc * Cc);
  ushort_t* wdkvT = alloc((size_t)KVRc * Cc);
  ushort_t* wkrT  = alloc((size_t)(Hc * RDc) * Cc);
  ushort_t* wuqT  = alloc((size_t)(Hc * HDc) * QRc);
  ushort_t* wqrT  = alloc((size_t)(Hc * RDc) * QRc);
  ushort_t* wukT  = alloc((size_t)(Hc * HDc) * KVRc);
  ushort_t* wuvT  = alloc((size_t)(Hc * HDc) * KVRc);
  ushort_t* woT   = alloc((size_t)Cc * (Hc * HDc));
  ushort_t* comb1 = alloc((size_t)Mx * 1536);   // [cq 1024 | ckv 512]
  ushort_t* Qa    = alloc((size_t)Bc * Hc * Tc * 192);
  ushort_t* Ka    = alloc((size_t)Bc * Hc * Tc * 192);
  ushort_t* vT    = alloc((size_t)Bc * Hc * HDc * Tc);
  ushort_t* O     = xb;  // alias: xb dead after GEMM1

  // prep1: x cast + GEMM1's three weight transposes (dq/dkv/kr)
  prep1<<<dim3(13312), 256, 0, stream>>>(x, xb, w_dq, w_dkv, w_kr, wdqT, wdkvT, wkrT);

  // GEMM1 (160 tiles) + remaining 5 weight transposes folded in (4608 routed blocks)
  gemm1f<<<dim3(4768), 512, 0, stream>>>(
      xb, Cc, wdqT, comb1, Cc, Ka, fc, fs,
      w_uq, wuqT, w_qr, wqrT, w_uk, wukT, w_uv, wuvT, w_o, woT);

  // GEMM2+3 fused: cq @ [w_uq|w_qr] -> Qa ; ckv @ [w_uk|w_uv] -> Ka(kc) + vT (transposed)
  gemm23<<<dim3(448), 512, 0, stream>>>(comb1, wuqT, comb1 + QRc, wukT, vT, Qa, Ka, fc, fs);

  attn_kernel<<<dim3(Bc * Hc, 16), 512, 0, stream>>>(Qa, Ka, vT, O);

  // GEMM4: O @ w_o -> out [4096][2048] fp32, 256x128 tiles = 256 blocks (full fill)
  gemm4_128<<<dim3(256), 512, 0, stream>>>(O, Hc * HDc, woT, out, Mx, Cc, Hc * HDc);
}

// Round 19
// 273.251 us; speedup vs baseline: 1.8059x; 1.8059x over previous
//
#include <hip/hip_runtime.h>

typedef unsigned short ushort_t;
typedef __attribute__((ext_vector_type(8))) short bs8;       // 8 x bf16 (4 VGPR)
typedef __attribute__((ext_vector_type(4))) float f32x4;
typedef __attribute__((ext_vector_type(4))) unsigned short u16x4;

#define DEV __device__ __forceinline__

DEV unsigned short f2bf(float f){
  unsigned u = __float_as_uint(f);
  u += 0x7fffu + ((u >> 16) & 1u);           // round-to-nearest-even
  return (unsigned short)(u >> 16);
}
DEV float bf2f(unsigned short h){ return __uint_as_float(((unsigned)h) << 16); }

DEV unsigned cvt_pk_bf16(float lo, float hi){
  unsigned r;
  asm volatile("v_cvt_pk_bf16_f32 %0, %1, %2" : "=v"(r) : "v"(lo), "v"(hi));
  return r;
}

DEV void gl2lds16(const void* g, void* l){
  __builtin_amdgcn_global_load_lds((const __attribute__((address_space(1))) void*)g,
                                   (__attribute__((address_space(3))) void*)l, 16, 0, 0);
}

DEV void st_out(ushort_t* C, size_t i, float v){ C[i] = f2bf(v); }
DEV void st_out(float*    C, size_t i, float v){ C[i] = v; }

// ---- prep_all: x cast (blocks >= 14336) + all weight transpose-casts in ONE dispatch ----
__global__ __launch_bounds__(256) void prep_all(
    const float* __restrict__ x, ushort_t* __restrict__ xb,
    const float* __restrict__ s0, const float* __restrict__ s1,
    const float* __restrict__ s2, const float* __restrict__ s3,
    const float* __restrict__ s4, const float* __restrict__ s5,
    const float* __restrict__ s6, const float* __restrict__ s7,
    ushort_t* __restrict__ d0, ushort_t* __restrict__ d1,
    ushort_t* __restrict__ d2, ushort_t* __restrict__ d3,
    ushort_t* __restrict__ d4, ushort_t* __restrict__ d5,
    ushort_t* __restrict__ d6, ushort_t* __restrict__ d7){
  const int bid = blockIdx.x;
  if (bid >= 14336){
    size_t i = ((size_t)(bid - 14336) * 256 + threadIdx.x) * 4;
    float4 v = *(const float4*)(x + i);
    u16x4 o;
    o[0] = f2bf(v.x); o[1] = f2bf(v.y); o[2] = f2bf(v.z); o[3] = f2bf(v.w);
    *(u16x4*)(xb + i) = o;
    return;
  }
  __shared__ float tile[32][33];
  const float* src; ushort_t* dst; int K, N, loc;
  if      (bid <  2048){ src=s0; dst=d0; K=2048; N=1024; loc=bid; }
  else if (bid <  3072){ src=s1; dst=d1; K=2048; N=512;  loc=bid-2048; }
  else if (bid <  5120){ src=s2; dst=d2; K=2048; N=1024; loc=bid-3072; }
  else if (bid <  7168){ src=s3; dst=d3; K=1024; N=2048; loc=bid-5120; }
  else if (bid <  8192){ src=s4; dst=d4; K=1024; N=1024; loc=bid-7168; }
  else if (bid <  9216){ src=s5; dst=d5; K=512;  N=2048; loc=bid-8192; }
  else if (bid < 10240){ src=s6; dst=d6; K=512;  N=2048; loc=bid-9216; }
  else                 { src=s7; dst=d7; K=2048; N=2048; loc=bid-10240; }
  const int nx = N >> 5;
  const int n0 = (loc % nx) << 5, k0 = (loc / nx) << 5;
  const int tx = threadIdx.x & 31, ty = threadIdx.x >> 5;
  for (int r = ty; r < 32; r += 8)
    tile[r][tx] = src[(size_t)(k0 + r) * N + n0 + tx];
  __syncthreads();
  for (int r = ty; r < 32; r += 8)
    dst[(size_t)(n0 + r) * K + k0 + tx] = f2bf(tile[tx][r]);
}

// ================= 256x256 8-phase GEMM core (T2+T3+T4+T5), BK=64 =================
DEV void gemm_core(const ushort_t* __restrict__ A, int lda,
                   const ushort_t* __restrict__ BT, int K,
                   int m0, int n0, ushort_t* lds, f32x4 (&acc)[8][4]){
  const int tid = threadIdx.x, lane = tid & 63, wid = tid >> 6;
  const int l15 = lane & 15, lhi = lane >> 4;
  const int wr = wid >> 2, wc = wid & 3;

  const int trow = tid >> 3;
  const int tcsrc = (tid & 7) ^ (trow & 7);
  const ushort_t* gA[2][2];
  const ushort_t* gB[2][2];
#pragma unroll
  for (int h = 0; h < 2; ++h)
#pragma unroll
    for (int i = 0; i < 2; ++i){
      gA[h][i] = A  + (size_t)(m0 + h * 128 + i * 64 + trow) * lda + tcsrc * 8;
      gB[h][i] = BT + (size_t)(n0 + h * 128 + i * 64 + trow) * K   + tcsrc * 8;
    }

  auto STAGE_A = [&](int buf, int h, int kt){
    gl2lds16(gA[h][0] + (size_t)kt * 64, lds + buf * 32768 + h * 8192 + tid * 8);
    gl2lds16(gA[h][1] + (size_t)kt * 64, lds + buf * 32768 + h * 8192 + 4096 + tid * 8);
  };
  auto STAGE_B = [&](int buf, int h, int kt){
    gl2lds16(gB[h][0] + (size_t)kt * 64, lds + buf * 32768 + 16384 + h * 8192 + tid * 8);
    gl2lds16(gB[h][1] + (size_t)kt * 64, lds + buf * 32768 + 16384 + h * 8192 + 4096 + tid * 8);
  };

  const int ck0 = ((lhi) ^ (l15 & 7)) << 3;
  const int ck1 = ((4 + lhi) ^ (l15 & 7)) << 3;

  bs8 aF[4][2], bLo[2][2], bHi[2][2];

  auto RDA = [&](int buf, int mq){
#pragma unroll
    for (int m = 0; m < 4; ++m){
      const ushort_t* r = lds + buf * 32768 + wr * 8192 + ((mq + m) * 16 + l15) * 64;
      aF[m][0] = *(const bs8*)(r + ck0);
      aF[m][1] = *(const bs8*)(r + ck1);
    }
  };
  auto RDB = [&](int buf, int nq, bs8 (&br)[2][2]){
#pragma unroll
    for (int n = 0; n < 2; ++n){
      const ushort_t* r = lds + buf * 32768 + 16384 + (wc >> 1) * 8192 +
                          ((wc & 1) * 64 + (nq + n) * 16 + l15) * 64;
      br[n][0] = *(const bs8*)(r + ck0);
      br[n][1] = *(const bs8*)(r + ck1);
    }
  };
  auto MMA = [&](int mq, int nq, bs8 (&br)[2][2]){
    __builtin_amdgcn_s_setprio(1);
#pragma unroll
    for (int m = 0; m < 4; ++m)
#pragma unroll
      for (int n = 0; n < 2; ++n){
        acc[mq + m][nq + n] = __builtin_amdgcn_mfma_f32_16x16x32_bf16(aF[m][0], br[n][0], acc[mq + m][nq + n], 0, 0, 0);
        acc[mq + m][nq + n] = __builtin_amdgcn_mfma_f32_16x16x32_bf16(aF[m][1], br[n][1], acc[mq + m][nq + n], 0, 0, 0);
      }
    __builtin_amdgcn_s_setprio(0);
  };

#define BAR() __builtin_amdgcn_s_barrier()
#define LGK() asm volatile("s_waitcnt lgkmcnt(0)" ::: "memory")
#define VMC4() asm volatile("s_waitcnt vmcnt(4)" ::: "memory")

  const int nkt = K >> 6;
  const int nIter = K >> 7;

  STAGE_A(0, 0, 0); STAGE_A(0, 1, 0); STAGE_B(0, 0, 0); STAGE_B(0, 1, 0);
  STAGE_B(1, 0, 1); STAGE_B(1, 1, 1);
  VMC4();
  BAR();

  for (int it = 0; it < nIter; ++it){
    const int kt1 = 2 * it + 1;
    int kt2 = 2 * it + 2; if (kt2 > nkt - 1) kt2 = nkt - 1;
    int kt3 = 2 * it + 3; if (kt3 > nkt - 1) kt3 = nkt - 1;
    RDA(0, 0); RDB(0, 0, bLo);
    STAGE_A(1, 0, kt1);
    BAR(); LGK(); MMA(0, 0, bLo); BAR();
    RDB(0, 2, bHi);
    STAGE_A(1, 1, kt1);
    BAR(); LGK(); MMA(0, 2, bHi); BAR();
    RDA(0, 4);
    STAGE_B(0, 0, kt2);
    BAR(); LGK(); MMA(4, 0, bLo); BAR();
    STAGE_B(0, 1, kt2);
    BAR(); LGK(); MMA(4, 2, bHi);
    VMC4(); BAR();
    RDA(1, 0); RDB(1, 0, bLo);
    STAGE_A(0, 0, kt2);
    BAR(); LGK(); MMA(0, 0, bLo); BAR();
    RDB(1, 2, bHi);
    STAGE_A(0, 1, kt2);
    BAR(); LGK(); MMA(0, 2, bHi); BAR();
    RDA(1, 4);
    STAGE_B(1, 0, kt3);
    BAR(); LGK(); MMA(4, 0, bLo); BAR();
    STAGE_B(1, 1, kt3);
    BAR(); LGK(); MMA(4, 2, bHi);
    VMC4(); BAR();
  }
#undef BAR
#undef LGK
#undef VMC4
}

// EPI 1: comb1[4096][1536] + rope(kr)->Ka. EPI 2: Qa (qc+rope(qr)) pre-scaled.
// EPI 3: Ka(kc) + v transposed -> vT[bh][d][t].
template<int EPI, typename OT>
DEV void gemm_epi(f32x4 (&acc)[8][4], OT* __restrict__ C, int N, int m0, int n0,
                  ushort_t* __restrict__ aux,
                  const float* __restrict__ fcp, const float* __restrict__ fsp){
  const int tid = threadIdx.x, lane = tid & 63, wid = tid >> 6;
  const int l15 = lane & 15, lhi = lane >> 4;
  const int wr = wid >> 2, wc = wid & 3;
  const float SC = (EPI == 2) ? (0.07216878364870323f * 1.4426950408889634f) : 1.0f;
  const int RBASE = (EPI == 1) ? 1536 : 2048;
#pragma unroll
  for (int m = 0; m < 8; ++m){
    const int r = m0 + wr * 128 + m * 16 + lhi * 4;
#pragma unroll
    for (int n = 0; n < 4; ++n){
      const int c = n0 + wc * 64 + n * 16 + l15;
      if (EPI == 0){
#pragma unroll
        for (int j = 0; j < 4; ++j)
          st_out(C, (size_t)(r + j) * N + c, acc[m][n][j]);
      } else if ((EPI == 1 && c < 1536)){
#pragma unroll
        for (int j = 0; j < 4; ++j)
          C[(size_t)(r + j) * 1536 + c] = (OT)f2bf(acc[m][n][j]);
      } else if (EPI == 2 && c < 2048){
        int hh = c >> 7, d = c & 127;
#pragma unroll
        for (int j = 0; j < 4; ++j){
          int rr = r + j, bb = rr >> 11, tt = rr & 2047;
          aux[((size_t)(bb * 16 + hh) * 2048 + tt) * 192 + d] = f2bf(acc[m][n][j] * SC);
        }
      } else if (EPI == 3 && c < 2048){
        int hh = c >> 7, d = c & 127;
#pragma unroll
        for (int j = 0; j < 4; ++j){
          int rr = r + j, bb = rr >> 11, tt = rr & 2047;
          aux[((size_t)(bb * 16 + hh) * 2048 + tt) * 192 + d] = f2bf(acc[m][n][j]);
        }
      } else if (EPI == 3){
        int cv = c - 2048;
        int hh = cv >> 7, d = cv & 127;
        int bb = r >> 11, tt = r & 2047;
        u16x4 o;
#pragma unroll
        for (int j = 0; j < 4; ++j) o[j] = f2bf(acc[m][n][j]);
        *(u16x4*)((ushort_t*)C + ((size_t)(bb * 16 + hh) * 128 + d) * 2048 + tt) = o;
      } else {
        int cr = c - RBASE;
        int hh = cr >> 6, dr = cr & 63, ii = dr >> 1;
#pragma unroll
        for (int j = 0; j < 4; ++j){
          int rr = r + j, bb = rr >> 11, tt = rr & 2047;
          float v = acc[m][n][j] * SC;
          float pv = __shfl_xor(v, 1);
          float co = fcp[tt * 32 + ii], si = fsp[tt * 32 + ii];
          float o = (l15 & 1) ? fmaf(pv, si, v * co) : fmaf(-pv, si, v * co);
          aux[((size_t)(bb * 16 + hh) * 2048 + tt) * 192 + 128 + dr] = f2bf(o);
        }
      }
    }
  }
}

template<int EPI, typename OT>
__global__ __launch_bounds__(512, 2) void gemm256(const ushort_t* __restrict__ A, int lda,
                                                  const ushort_t* __restrict__ BT,
                                                  OT* __restrict__ C,
                                                  int M, int N, int K,
                                                  ushort_t* __restrict__ aux,
                                                  const float* __restrict__ fcp,
                                                  const float* __restrict__ fsp){
  __shared__ __align__(16) ushort_t lds[65536];
  const int nbx = M >> 8;
  const int nwg = gridDim.x;
  const int orig = blockIdx.x;
  const int wg = (orig & 7) * (nwg >> 3) + (orig >> 3);
  const int m0 = (wg % nbx) << 8;
  const int n0 = (wg / nbx) << 8;
  f32x4 acc[8][4] = {};
  gemm_core(A, lda, BT, K, m0, n0, lds, acc);
  gemm_epi<EPI, OT>(acc, C, N, m0, n0, aux, fcp, fsp);
}

// GEMM2 (192 blocks) + GEMM3 (256 blocks) fused: 448 blocks.
__global__ __launch_bounds__(512, 2) void gemm23(const ushort_t* __restrict__ A2,
                                                 const ushort_t* __restrict__ BT2,
                                                 const ushort_t* __restrict__ A3,
                                                 const ushort_t* __restrict__ BT3,
                                                 ushort_t* __restrict__ vT,
                                                 ushort_t* __restrict__ Qa,
                                                 ushort_t* __restrict__ Ka,
                                                 const float* __restrict__ fcp,
                                                 const float* __restrict__ fsp){
  __shared__ __align__(16) ushort_t lds[65536];
  const int nwg = gridDim.x;   // 448
  const int orig = blockIdx.x;
  const int wg = (orig & 7) * (nwg >> 3) + (orig >> 3);
  f32x4 acc[8][4] = {};
  if (wg < 192){
    const int m0 = (wg % 16) << 8, n0 = (wg / 16) << 8;
    gemm_core(A2, 1536, BT2, 1024, m0, n0, lds, acc);
    gemm_epi<2, ushort_t>(acc, nullptr, 3072, m0, n0, Qa, fcp, fsp);
  } else {
    const int g = wg - 192;
    const int m0 = (g % 16) << 8, n0 = (g / 16) << 8;
    gemm_core(A3, 1536, BT3, 512, m0, n0, lds, acc);
    gemm_epi<3, ushort_t>(acc, vT, 4096, m0, n0, Ka, fcp, fsp);
  }
}

// ============ GEMM4: 256x128-tile 8-phase core (BK=64), fp32 out, 256 blocks ============
__global__ __launch_bounds__(512, 1) void gemm4_128(const ushort_t* __restrict__ A, int lda,
                                                    const ushort_t* __restrict__ BT,
                                                    float* __restrict__ C,
                                                    int M, int N, int K){
  __shared__ __align__(16) ushort_t lds[49152];
  const int tid = threadIdx.x, lane = tid & 63, wid = tid >> 6;
  const int l15 = lane & 15, lhi = lane >> 4;
  const int wr = wid >> 1, wc = wid & 1;

  const int nbx = M >> 8;
  const int nwg = gridDim.x;
  const int orig = blockIdx.x;
  const int wg = (orig & 7) * (nwg >> 3) + (orig >> 3);
  const int m0 = (wg % nbx) << 8;
  const int n0 = (wg / nbx) << 7;

  const int trow = tid >> 3;
  const int tcsrc = (tid & 7) ^ (trow & 7);
  const ushort_t* gA[2][2];
  const ushort_t* gB[2];
#pragma unroll
  for (int h = 0; h < 2; ++h)
#pragma unroll
    for (int i = 0; i < 2; ++i)
      gA[h][i] = A + (size_t)(m0 + h * 128 + i * 64 + trow) * lda + tcsrc * 8;
#pragma unroll
  for (int i = 0; i < 2; ++i)
    gB[i] = BT + (size_t)(n0 + i * 64 + trow) * K + tcsrc * 8;

  auto STAGE_A = [&](int buf, int h, int kt){
    gl2lds16(gA[h][0] + (size_t)kt * 64, lds + buf * 24576 + h * 8192 + tid * 8);
    gl2lds16(gA[h][1] + (size_t)kt * 64, lds + buf * 24576 + h * 8192 + 4096 + tid * 8);
  };
  auto STAGE_B = [&](int buf, int kt){
    gl2lds16(gB[0] + (size_t)kt * 64, lds + buf * 24576 + 16384 + tid * 8);
    gl2lds16(gB[1] + (size_t)kt * 64, lds + buf * 24576 + 16384 + 4096 + tid * 8);
  };

  const int ck0 = ((lhi) ^ (l15 & 7)) << 3;
  const int ck1 = ((4 + lhi) ^ (l15 & 7)) << 3;

  f32x4 acc[4][4] = {};
  bs8 aF[2][2], bLo[2][2], bHi[2][2];

  auto RDA = [&](int buf, int mq){
#pragma unroll
    for (int m = 0; m < 2; ++m){
      const int rowin = (wr & 1) * 64 + (mq + m) * 16 + l15;
      const ushort_t* r = lds + buf * 24576 + (wr >> 1) * 8192 + rowin * 64;
      aF[m][0] = *(const bs8*)(r + ck0);
      aF[m][1] = *(const bs8*)(r + ck1);
    }
  };
  auto RDB = [&](int buf, int nq, bs8 (&br)[2][2]){
#pragma unroll
    for (int n = 0; n < 2; ++n){
      const int row = wc * 64 + (nq + n) * 16 + l15;
      const ushort_t* r = lds + buf * 24576 + 16384 + row * 64;
      br[n][0] = *(const bs8*)(r + ck0);
      br[n][1] = *(const bs8*)(r + ck1);
    }
  };
  auto MMA = [&](int mq, int nq, bs8 (&br)[2][2]){
    __builtin_amdgcn_s_setprio(1);
#pragma unroll
    for (int m = 0; m < 2; ++m)
#pragma unroll
      for (int n = 0; n < 2; ++n){
        acc[mq + m][nq + n] = __builtin_amdgcn_mfma_f32_16x16x32_bf16(aF[m][0], br[n][0], acc[mq + m][nq + n], 0, 0, 0);
        acc[mq + m][nq + n] = __builtin_amdgcn_mfma_f32_16x16x32_bf16(aF[m][1], br[n][1], acc[mq + m][nq + n], 0, 0, 0);
      }
    __builtin_amdgcn_s_setprio(0);
  };

#define BAR() __builtin_amdgcn_s_barrier()
#define LGK() asm volatile("s_waitcnt lgkmcnt(0)" ::: "memory")
#define VMC2() asm volatile("s_waitcnt vmcnt(2)" ::: "memory")

  const int nkt = K >> 6;
  const int nIter = K >> 7;

  STAGE_A(0, 0, 0); STAGE_A(0, 1, 0); STAGE_B(0, 0);
  STAGE_B(1, 1);
  VMC2();
  BAR();

  for (int it = 0; it < nIter; ++it){
    const int kt1 = 2 * it + 1;
    int kt2 = 2 * it + 2; if (kt2 > nkt - 1) kt2 = nkt - 1;
    int kt3 = 2 * it + 3; if (kt3 > nkt - 1) kt3 = nkt - 1;
    RDA(0, 0); RDB(0, 0, bLo);
    STAGE_A(1, 0, kt1);
    BAR(); LGK(); MMA(0, 0, bLo); BAR();
    RDB(0, 2, bHi);
    STAGE_A(1, 1, kt1);
    BAR(); LGK(); MMA(0, 2, bHi); BAR();
    RDA(0, 2);
    STAGE_B(0, kt2);
    BAR(); LGK(); MMA(2, 0, bLo); BAR();
    BAR(); LGK(); MMA(2, 2, bHi);
    VMC2(); BAR();
    RDA(1, 0); RDB(1, 0, bLo);
    STAGE_A(0, 0, kt2);
    BAR(); LGK(); MMA(0, 0, bLo); BAR();
    RDB(1, 2, bHi);
    STAGE_A(0, 1, kt2);
    BAR(); LGK(); MMA(0, 2, bHi); BAR();
    RDA(1, 2);
    STAGE_B(1, kt3);
    BAR(); LGK(); MMA(2, 0, bLo); BAR();
    BAR(); LGK(); MMA(2, 2, bHi);
    VMC2(); BAR();
  }
#undef BAR
#undef LGK
#undef VMC2

#pragma unroll
  for (int m = 0; m < 4; ++m){
    const int r = m0 + wr * 64 + m * 16 + lhi * 4;
#pragma unroll
    for (int n = 0; n < 4; ++n){
      const int c = n0 + wc * 64 + n * 16 + l15;
#pragma unroll
      for (int j = 0; j < 4; ++j)
        C[(size_t)(r + j) * N + c] = acc[m][n][j];
    }
  }
}

// ====== flash attention v10b: balanced pairing + max3 reduction tree ======
__global__ __launch_bounds__(512) void attn_kernel(const ushort_t* __restrict__ Qa,
                                                   const ushort_t* __restrict__ Ka,
                                                   const ushort_t* __restrict__ VT,
                                                   ushort_t* __restrict__ O){
  __shared__ __align__(16) ushort_t lds[40960];
  const int tid = threadIdx.x, lane = tid & 63, wid = tid >> 6;
  const int bh = blockIdx.x;
  const int y = blockIdx.y;
  const int qb = (y < 8) ? (15 - y) : (y - 8);   // CU pair sums to 15 everywhere
  const int b = bh >> 4, h = bh & 15;
  const int qm0 = qb << 7;
  const int nkt = 2 * qb + 2;
  const int l15 = lane & 15, lhi = lane >> 4;

  const ushort_t* Kbh = Ka + (size_t)bh * 2048 * 192;
  const ushort_t* Vbh = VT + (size_t)bh * 128 * 2048;

  const ushort_t* ksrc[3];
#pragma unroll
  for (int i = 0; i < 3; ++i){
    int c = i * 512 + tid;
    int row = c / 24, col = c % 24;
    int hk = (row & 3) | (((row >> 3) & 1) << 2);
    ksrc[i] = Kbh + (size_t)row * 192 + (col ^ hk) * 8;
  }
  const ushort_t* vsrc[2];
#pragma unroll
  for (int i = 0; i < 2; ++i){
    int c = i * 512 + tid;
    int d = c >> 3, col = c & 7;
    vsrc[i] = Vbh + (size_t)d * 2048 + (col ^ (d & 7)) * 8;
  }

  auto STAGE = [&](int kt, int buf){
#pragma unroll
    for (int i = 0; i < 3; ++i)
      gl2lds16(ksrc[i] + (size_t)kt * 12288, lds + buf * 12288 + (i * 512 + tid) * 8);
#pragma unroll
    for (int i = 0; i < 2; ++i)
      gl2lds16(vsrc[i] + kt * 64, lds + 24576 + buf * 8192 + (i * 512 + tid) * 8);
  };

  bs8 qf[6];
  {
    const size_t qrow = ((size_t)bh * 2048 + qm0 + wid * 16 + l15) * 192;
#pragma unroll
    for (int kc = 0; kc < 6; ++kc)
      qf[kc] = *(const bs8*)(Qa + qrow + kc * 32 + lhi * 8);
  }

  f32x4 acc[8] = {};
  float mrow = -1e30f, lrow = 0.f;

  const int mylast = 2 * qb + (wid >> 2);
  const int hkr = (l15 & 3) | (((l15 >> 2) & 1) << 2);

#define BARR() __builtin_amdgcn_s_barrier()
#define LGK0() asm volatile("s_waitcnt lgkmcnt(0)" ::: "memory")
#define VMC(n) asm volatile("s_waitcnt vmcnt(" #n ")" ::: "memory")

  STAGE(0, 0);
  STAGE(1, 1);
  VMC(5);
  BARR();

  for (int kt = 0; kt < nkt; ++kt){
    const int cur = kt & 1;
    const ushort_t* Kb = lds + cur * 12288;
    const ushort_t* Vb = lds + 24576 + cur * 8192;

    if (kt <= mylast){
      f32x4 s[4] = {};
      __builtin_amdgcn_s_setprio(1);
#pragma unroll
      for (int kc = 0; kc < 6; ++kc){
        bs8 kf4[4];
#pragma unroll
        for (int m = 0; m < 4; ++m){
          int row = ((m >> 1) << 5) + ((l15 >> 2) << 3) + ((m & 1) << 2) + (l15 & 3);
          kf4[m] = *(const bs8*)(Kb + row * 192 + (((kc * 4 + lhi) ^ hkr) << 3));
        }
#pragma unroll
        for (int m = 0; m < 4; ++m)
          s[m] = __builtin_amdgcn_mfma_f32_16x16x32_bf16(kf4[m], qf[kc], s[m], 0, 0, 0);
      }
      __builtin_amdgcn_s_setprio(0);

      const bool noMask = (kt * 64 + 63) <= (qm0 + wid * 16);
      const int qi = qm0 + wid * 16 + l15;
      if (!noMask){
#pragma unroll
        for (int m = 0; m < 4; ++m)
#pragma unroll
          for (int j = 0; j < 4; ++j){
            int ki = kt * 64 + ((m >> 1) << 5) + (lhi << 3) + ((m & 1) << 2) + j;
            if (ki > qi) s[m][j] = -3e38f;
          }
      }
      float r0 = fmaxf(fmaxf(s[0][0], s[0][1]), s[0][2]);
      float r1 = fmaxf(fmaxf(s[0][3], s[1][0]), s[1][1]);
      float r2 = fmaxf(fmaxf(s[1][2], s[1][3]), s[2][0]);
      float r3 = fmaxf(fmaxf(s[2][1], s[2][2]), s[2][3]);
      float r4 = fmaxf(fmaxf(s[3][0], s[3][1]), s[3][2]);
      float rmax = fmaxf(fmaxf(r0, r1), fmaxf(fmaxf(r2, r3), fmaxf(r4, s[3][3])));
      rmax = fmaxf(rmax, __shfl_xor(rmax, 16));
      rmax = fmaxf(rmax, __shfl_xor(rmax, 32));
      if (!__all(rmax <= mrow + 8.f)){
        float mnew = fmaxf(mrow, rmax);
        float osc = exp2f(mrow - mnew);
        lrow *= osc;
#pragma unroll
        for (int f = 0; f < 8; ++f) acc[f] *= osc;
        mrow = mnew;
      }
      float rsum = 0.f;
#pragma unroll
      for (int m = 0; m < 4; ++m)
#pragma unroll
        for (int j = 0; j < 4; ++j){
          float pv = exp2f(s[m][j] - mrow);
          s[m][j] = pv;
          rsum += pv;
        }
      rsum += __shfl_xor(rsum, 16);
      rsum += __shfl_xor(rsum, 32);
      lrow += rsum;

      bs8 pb[2];
#pragma unroll
      for (int kc2 = 0; kc2 < 2; ++kc2){
        union { bs8 v; unsigned u[4]; } pu;
#pragma unroll
        for (int half = 0; half < 2; ++half){
          const f32x4& sv = s[2 * kc2 + half];
          pu.u[2 * half]     = cvt_pk_bf16(sv[0], sv[1]);
          pu.u[2 * half + 1] = cvt_pk_bf16(sv[2], sv[3]);
        }
        pb[kc2] = pu.v;
      }

      __builtin_amdgcn_s_setprio(1);
#pragma unroll
      for (int kc2 = 0; kc2 < 2; ++kc2)
#pragma unroll
        for (int f = 0; f < 8; ++f){
          bs8 vf = *(const bs8*)(Vb + (f * 16 + l15) * 64 + (((kc2 * 4 + lhi) ^ (l15 & 7)) << 3));
          acc[f] = __builtin_amdgcn_mfma_f32_16x16x32_bf16(vf, pb[kc2], acc[f], 0, 0, 0);
        }
      __builtin_amdgcn_s_setprio(0);
    }

    LGK0();
    BARR();
    if (kt + 2 < nkt){
      STAGE(kt + 2, cur);
      VMC(5);
    } else {
      VMC(0);
    }
    BARR();
  }
#undef BARR
#undef LGK0
#undef VMC

  {
    float rl = 1.0f / lrow;
    int t = qm0 + wid * 16 + l15;
#pragma unroll
    for (int f = 0; f < 8; ++f){
      u16x4 o;
#pragma unroll
      for (int j = 0; j < 4; ++j) o[j] = f2bf(acc[f][j] * rl);
      *(u16x4*)(O + ((size_t)b * 2048 + t) * 2048 + h * 128 + f * 16 + lhi * 4) = o;
    }
  }
}

extern "C" void kernel_launch(void* const* d_in, const int* in_sizes, int n_in,
                              void* d_out, int out_size, void* d_ws, size_t ws_size,
                              hipStream_t stream){
  constexpr int Bc = 2, Tc = 2048, Cc = 2048, Hc = 16, HDc = 128, RDc = 64, KVRc = 512, QRc = 1024;
  constexpr int Mx = Bc * Tc; // 4096
  const float* x     = (const float*)d_in[0];
  const float* w_dq  = (const float*)d_in[1];
  const float* w_uq  = (const float*)d_in[2];
  const float* w_dkv = (const float*)d_in[3];
  const float* w_uk  = (const float*)d_in[4];
  const float* w_uv  = (const float*)d_in[5];
  const float* w_qr  = (const float*)d_in[6];
  const float* w_kr  = (const float*)d_in[7];
  const float* w_o   = (const float*)d_in[8];
  const float* fc    = (const float*)d_in[9];
  const float* fs    = (const float*)d_in[10];
  float* out = (float*)d_out;

  char* ws = (char*)d_ws;
  size_t off = 0;
  auto alloc = [&](size_t elems) -> ushort_t* {
    ushort_t* p = (ushort_t*)(ws + off);
    off += ((elems * 2) + 255) & ~(size_t)255;
    return p;
  };
  ushort_t* xb    = alloc((size_t)Mx * Cc);
  ushort_t* wdqT  = alloc((size_t)QRc * Cc);
  ushort_t* wdkvT = alloc((size_t)KVRc * Cc);
  ushort_t* wkrT  = alloc((size_t)(Hc * RDc) * Cc);
  ushort_t* wuqT  = alloc((size_t)(Hc * HDc) * QRc);
  ushort_t* wqrT  = alloc((size_t)(Hc * RDc) * QRc);
  ushort_t* wukT  = alloc((size_t)(Hc * HDc) * KVRc);
  ushort_t* wuvT  = alloc((size_t)(Hc * HDc) * KVRc);
  ushort_t* woT   = alloc((size_t)Cc * (Hc * HDc));
  ushort_t* comb1 = alloc((size_t)Mx * 1536);   // [cq 1024 | ckv 512]
  ushort_t* Qa    = alloc((size_t)Bc * Hc * Tc * 192);
  ushort_t* Ka    = alloc((size_t)Bc * Hc * Tc * 192);
  ushort_t* vT    = alloc((size_t)Bc * Hc * HDc * Tc);
  ushort_t* O     = xb;  // alias: xb dead after GEMM1

  // prep: x cast + all 8 weight transpose-casts in one dispatch
  prep_all<<<dim3(14336 + 8192), 256, 0, stream>>>(x, xb,
      w_dq, w_dkv, w_kr, w_uq, w_qr, w_uk, w_uv, w_o,
      wdqT, wdkvT, wkrT, wuqT, wqrT, wukT, wuvT, woT);

  // GEMM1: x @ [w_dq|w_dkv|w_kr] -> comb1[.][1536] + rope(kr)->Ka[..][128..192)
  gemm256<1, ushort_t><<<dim3((Mx / 256) * (2560 / 256)), 512, 0, stream>>>(
      xb, Cc, wdqT, comb1, Mx, 2560, Cc, Ka, fc, fs);
  // GEMM2+3 fused: cq @ [w_uq|w_qr] -> Qa ; ckv @ [w_uk|w_uv] -> Ka(kc) + vT (transposed)
  gemm23<<<dim3(448), 512, 0, stream>>>(comb1, wuqT, comb1 + QRc, wukT, vT, Qa, Ka, fc, fs);

  attn_kernel<<<dim3(Bc * Hc, 16), 512, 0, stream>>>(Qa, Ka, vT, O);

  // GEMM4: O @ w_o -> out [4096][2048] fp32, 256x128 tiles = 256 blocks (full fill)
  gemm4_128<<<dim3(256), 512, 0, stream>>>(O, Hc * HDc, woT, out, Mx, Cc, Hc * HDc);
}